// Round 22
// baseline (1053.295 us; speedup 1.0000x reference)
//
#include <hip/hip_runtime.h>
#include <hip/hip_bf16.h>

// ---------------------------------------------------------------------------
// StackGCNEncoder on MI355X — round 22:
//   GEMM re-tiled 256x128 (4 waves, wave tile 128x64): 32 MFMA + 12 ds_read
//   per 2-barrier K-step (2x barrier amortization vs r21's 16) at 48 KB LDS
//   -> 3 blocks/CU kept. XOR swizzle / counted vmcnt(6) / XCD swizzle carried.
//   Everything else identical to round 21.
// ---------------------------------------------------------------------------

typedef unsigned short u16;
typedef short s16x8 __attribute__((ext_vector_type(8)));
typedef float f32x4 __attribute__((ext_vector_type(4)));
typedef __attribute__((ext_vector_type(8))) unsigned short u16x8;
typedef unsigned long long u64;

__device__ __forceinline__ u16 f2bf(float x) {            // RNE f32->bf16
    unsigned u = __float_as_uint(x);
    return (u16)((u + 0x7fff + ((u >> 16) & 1)) >> 16);
}
__device__ __forceinline__ float bf2f(u16 h) {
    return __uint_as_float(((unsigned)h) << 16);
}

__device__ __forceinline__ void gload16(const u16* g, u16* l) {
    __builtin_amdgcn_global_load_lds(
        (const __attribute__((address_space(1))) unsigned int*)g,
        (__attribute__((address_space(3))) unsigned int*)l,
        16, 0, 0);
}

// ---------------------------------------------------------------------------
// bf16 GEMM, 256x128 tile, 4 waves (2M x 2N), wave tile 128x64, BK=32.
// LDS buffer 24 KB: A[0..8191] (256r x 32c), B[8192..12287] (128r x 32c);
// dbuf 48 KB. phys chunk = logical ^ ((row>>1)&3); linear gload_lds dest.
// Counted vmcnt(6) barriers. Y all-bf16.
// ---------------------------------------------------------------------------
__global__ __launch_bounds__(256)
void gemm_bf16_kernel(const u16* __restrict__ Ah, const u16* __restrict__ Bh,
                      u16* __restrict__ Y, int ldy,
                      int K, int nxmask, int nxshift)
{
    __shared__ u16 lds[2][12288];   // 48 KB

    const int nwg = gridDim.x;
    const int q   = nwg >> 3, r8 = nwg & 7;
    const int xcd = blockIdx.x & 7, pos = blockIdx.x >> 3;
    const int lin = (xcd < r8 ? xcd * (q + 1) : r8 * (q + 1) + (xcd - r8) * q) + pos;
    const int bm0 = (lin >> nxshift) * 256;
    const int bn0 = (lin & nxmask) * 128;

    const int tid  = threadIdx.x;
    const int lane = tid & 63;
    const int wid  = tid >> 6;      // 0..3
    const int wr   = wid >> 1;      // 0..1 -> 128-row half
    const int wc   = wid & 1;       // 0..1 -> 64-col half

    // staging: thread covers A chunks {tid, tid+256, tid+512, tid+768} and
    // B chunks {tid, tid+256}; chunk c -> row c>>2, phys col chunk c&3,
    // logical col chunk = (c&3) ^ ((c>>3)&3) (invariant under +256).
    const int srow = tid >> 2;                       // 0..63
    const int scol = ((tid & 3) ^ ((tid >> 3) & 3)) * 8;   // u16 units
    size_t aoff0 = (size_t)(bm0 + srow) * K + scol;
    size_t aoff1 = (size_t)(bm0 + srow + 64) * K + scol;
    size_t aoff2 = (size_t)(bm0 + srow + 128) * K + scol;
    size_t aoff3 = (size_t)(bm0 + srow + 192) * K + scol;
    size_t boff0 = (size_t)(bn0 + srow) * K + scol;
    size_t boff1 = (size_t)(bn0 + srow + 64) * K + scol;
    const int c0 = tid * 8;          // A dest (u16), +2048 per chunk step
    const int bdst = 8192 + tid * 8;

    f32x4 zero = {0.f, 0.f, 0.f, 0.f};
    f32x4 acc[8][4];
    #pragma unroll
    for (int i = 0; i < 8; ++i)
        #pragma unroll
        for (int j = 0; j < 4; ++j) acc[i][j] = zero;

    // fragment reads: row = base + 16*frag + (lane&15); (row>>1)&3 = (lane>>1)&3
    const int fchunk = (((lane >> 4) ^ ((lane >> 1) & 3))) * 8;
    const int a_fr = (wr * 128 + (lane & 15)) * 32 + fchunk;
    const int b_fr = (wc * 64  + (lane & 15)) * 32 + fchunk;

    const int nk = K >> 5;

    {
        u16* L = lds[0];
        gload16(Ah + aoff0, L + c0);          gload16(Ah + aoff1, L + c0 + 2048);
        gload16(Ah + aoff2, L + c0 + 4096);   gload16(Ah + aoff3, L + c0 + 6144);
        gload16(Bh + boff0, L + bdst);        gload16(Bh + boff1, L + bdst + 2048);
    }
    int cur = 0;
    for (int t = 0; t < nk; ++t) {
        if (t + 1 < nk) {
            const int k0 = (t + 1) * 32;
            u16* L = lds[cur ^ 1];
            gload16(Ah + aoff0 + k0, L + c0);          gload16(Ah + aoff1 + k0, L + c0 + 2048);
            gload16(Ah + aoff2 + k0, L + c0 + 4096);   gload16(Ah + aoff3 + k0, L + c0 + 6144);
            gload16(Bh + boff0 + k0, L + bdst);        gload16(Bh + boff1 + k0, L + bdst + 2048);
            asm volatile("s_waitcnt vmcnt(6)\n\ts_barrier" ::: "memory");
        } else {
            asm volatile("s_waitcnt vmcnt(0)\n\ts_barrier" ::: "memory");
        }
        const u16* L = lds[cur];
        s16x8 bh[4];
        #pragma unroll
        for (int nf = 0; nf < 4; ++nf)
            bh[nf] = *(const s16x8*)(L + 8192 + b_fr + nf * 512);
        #pragma unroll
        for (int mf = 0; mf < 8; ++mf) {
            s16x8 ahv = *(const s16x8*)(L + a_fr + mf * 512);
            #pragma unroll
            for (int nf = 0; nf < 4; ++nf)
                acc[mf][nf] = __builtin_amdgcn_mfma_f32_16x16x32_bf16(ahv, bh[nf], acc[mf][nf], 0, 0, 0);
        }
        asm volatile("s_barrier" ::: "memory");
        cur ^= 1;
    }

    #pragma unroll
    for (int mf = 0; mf < 8; ++mf) {
        const int row0 = bm0 + wr * 128 + mf * 16 + (lane >> 4) * 4;
        #pragma unroll
        for (int nf = 0; nf < 4; ++nf) {
            const int col = bn0 + wc * 64 + nf * 16 + (lane & 15);
            #pragma unroll
            for (int r = 0; r < 4; ++r)
                Y[(size_t)(row0 + r) * ldy + col] = f2bf(acc[mf][nf][r]);
        }
    }
}

// ---------------------------------------------------------------------------
// f32 [M][1024] -> bf16 (8 elems/thread), zero-padded rows.
// ---------------------------------------------------------------------------
__global__ __launch_bounds__(256)
void cvt_bf16_kernel(const float* __restrict__ A, u16* __restrict__ Hh, int M)
{
    const size_t g  = (size_t)blockIdx.x * 256 + threadIdx.x;
    const size_t i8 = g * 8;
    const int row   = (int)(i8 >> 10);
    f32x4 a = {0.f, 0.f, 0.f, 0.f}, b = {0.f, 0.f, 0.f, 0.f};
    if (row < M) {
        a = *(const f32x4*)(A + i8);
        b = *(const f32x4*)(A + i8 + 4);
    }
    u16x8 h;
    #pragma unroll
    for (int j = 0; j < 4; ++j) { h[j] = f2bf(a[j]); h[4 + j] = f2bf(b[j]); }
    *(u16x8*)(Hh + i8) = h;
}

// ---------------------------------------------------------------------------
// fill16 standalone: 16 edges/thread, row-sliced XCD-affine, u16 rows.
// ---------------------------------------------------------------------------
__global__ __launch_bounds__(256)
void fill16_kernel(const u16* __restrict__ r16R, const int* __restrict__ colsR,
                   const float* __restrict__ valsR,
                   const u16* __restrict__ r16P, const int* __restrict__ colsP,
                   const float* __restrict__ valsP,
                   int* __restrict__ curR, int* __restrict__ curP,
                   int2* __restrict__ evR, int2* __restrict__ evP,
                   int NR, int NP, int E)
{
    const int fx    = blockIdx.x;
    const int s     = blockIdx.y;
    const int side  = blockIdx.z;
    const int slice = fx & 7;
    const int chunk = fx >> 3;
    const int N          = side ? NP : NR;
    const u16* r16       = side ? r16P : r16R;
    const int* cols      = side ? colsP : colsR;
    const float* vals    = side ? valsP : valsR;
    int* cursor          = side ? curP : curR;
    int2* ev             = side ? evP : evR;

    const int Nsl = (N + 7) >> 3;
    const int r0 = slice * Nsl;
    const int r1 = min(N, r0 + Nsl);

    const int e0 = chunk * 4096 + threadIdx.x * 16;
    if (e0 >= E) return;
    const size_t base = (size_t)s * E;

    if (e0 + 16 <= E) {
        u64 rq[4];
        #pragma unroll
        for (int g = 0; g < 4; ++g)
            rq[g] = *(const u64*)(r16 + base + e0 + g * 4);
        #pragma unroll
        for (int g = 0; g < 4; ++g) {
            #pragma unroll
            for (int j = 0; j < 4; ++j) {
                int r = (int)(u16)(rq[g] >> (16 * j));
                if (r >= r0 && r < r1) {
                    int idx = e0 + g * 4 + j;
                    int pos = atomicAdd(cursor + s * N + r, 1);
                    ev[base + pos] = make_int2(cols[base + idx],
                                               __float_as_int(vals[base + idx]));
                }
            }
        }
    } else {
        for (int j = 0; j < 16 && e0 + j < E; ++j) {
            int r = (int)r16[base + e0 + j];
            if (r >= r0 && r < r1) {
                int pos = atomicAdd(cursor + s * N + r, 1);
                ev[base + pos] = make_int2(cols[base + e0 + j],
                                           __float_as_int(vals[base + e0 + j]));
            }
        }
    }
}

__global__ __launch_bounds__(256)
void zero_u16_kernel(u16* __restrict__ a, int n)
{
    int i = blockIdx.x * 256 + threadIdx.x;
    if (i < n) a[i] = 0;
}

// ---------------------------------------------------------------------------
// CSR build
// ---------------------------------------------------------------------------
__global__ __launch_bounds__(256)
void zero2_i32_kernel(int* __restrict__ a, int na, int* __restrict__ b, int nb)
{
    int i = blockIdx.x * 256 + threadIdx.x;
    if (i < na) a[i] = 0;
    if (i < nb) b[i] = 0;
}

__global__ __launch_bounds__(256)
void pack_hist2_kernel(const int* __restrict__ rowsR, const int* __restrict__ rowsP,
                       u16* __restrict__ r16R, u16* __restrict__ r16P,
                       int* __restrict__ cntR, int* __restrict__ cntP,
                       int NR, int NP, int E)
{
    int s = blockIdx.y;
    int e = (blockIdx.x * 256 + threadIdx.x) * 4;
    if (e >= E) return;
    const int* rows = blockIdx.z ? rowsP : rowsR;
    u16* r16 = blockIdx.z ? r16P : r16R;
    int* cnt = blockIdx.z ? cntP : cntR;
    const int N = blockIdx.z ? NP : NR;
    size_t base = (size_t)s * E;
    if (e + 4 <= E) {
        int4 r4 = *(const int4*)(rows + base + e);
        u16 p[4] = {(u16)r4.x, (u16)r4.y, (u16)r4.z, (u16)r4.w};
        *(u64*)(r16 + base + e) = *(const u64*)p;
        atomicAdd(cnt + s * N + r4.x, 1);
        atomicAdd(cnt + s * N + r4.y, 1);
        atomicAdd(cnt + s * N + r4.z, 1);
        atomicAdd(cnt + s * N + r4.w, 1);
    } else {
        for (int j = 0; j < 4 && e + j < E; ++j) {
            int r = rows[base + e + j];
            r16[base + e + j] = (u16)r;
            atomicAdd(cnt + s * N + r, 1);
        }
    }
}

__global__ __launch_bounds__(256)
void scan_block2_kernel(const int* __restrict__ cR, int* __restrict__ rpR,
                        int* __restrict__ bsR, int NR, int np1R, int NBR,
                        const int* __restrict__ cP, int* __restrict__ rpP,
                        int* __restrict__ bsP, int NP, int np1P, int NBP)
{
    const int side = blockIdx.z;
    const int NB = side ? NBP : NBR;
    if ((int)blockIdx.x >= NB) return;
    const int N = side ? NP : NR;
    const int np1 = side ? np1P : np1R;
    const int* counts = side ? cP : cR;
    int* rowptr = side ? rpP : rpR;
    int* blocksum = side ? bsP : bsR;

    __shared__ int sd[256];
    int s = blockIdx.y;
    int i = blockIdx.x * 256 + threadIdx.x;
    int tid = threadIdx.x;
    int v = (i < N) ? counts[s * N + i] : 0;
    sd[tid] = v;
    __syncthreads();
    #pragma unroll
    for (int off = 1; off < 256; off <<= 1) {
        int t = (tid >= off) ? sd[tid - off] : 0;
        __syncthreads();
        sd[tid] += t;
        __syncthreads();
    }
    if (i < N) rowptr[s * np1 + i] = sd[tid] - v;
    if (tid == 255) blocksum[s * NB + blockIdx.x] = sd[255];
}

__global__ __launch_bounds__(256)
void scan_aux2_kernel(int* __restrict__ bsR, int NBR, int* __restrict__ bsP, int NBP)
{
    const int side = blockIdx.x >> 2;
    const int s = blockIdx.x & 3;
    int* blocksum = side ? bsP : bsR;
    const int NB = side ? NBP : NBR;

    __shared__ int sd[256];
    int tid = threadIdx.x;
    int v = (tid < NB) ? blocksum[s * NB + tid] : 0;
    sd[tid] = v;
    __syncthreads();
    #pragma unroll
    for (int off = 1; off < 256; off <<= 1) {
        int t = (tid >= off) ? sd[tid - off] : 0;
        __syncthreads();
        sd[tid] += t;
        __syncthreads();
    }
    if (tid < NB) blocksum[s * NB + tid] = sd[tid] - v;
}

__global__ __launch_bounds__(256)
void finalize2_kernel(int* __restrict__ rpR, const int* __restrict__ bsR,
                      int* __restrict__ curR, int NR, int np1R, int NBR,
                      int* __restrict__ rpP, const int* __restrict__ bsP,
                      int* __restrict__ curP, int NP, int np1P, int NBP, int E)
{
    const int side = blockIdx.z;
    const int NB = side ? NBP : NBR;
    if ((int)blockIdx.x >= NB) return;
    const int N = side ? NP : NR;
    const int np1 = side ? np1P : np1R;
    int* rowptr = side ? rpP : rpR;
    const int* blocksum = side ? bsP : bsR;
    int* cursor = side ? curP : curR;

    int s = blockIdx.y;
    int i = blockIdx.x * 256 + threadIdx.x;
    if (i < N) {
        int v = rowptr[s * np1 + i] + blocksum[s * NB + blockIdx.x];
        rowptr[s * np1 + i] = v;
        cursor[s * N + i] = v;
    }
    if (i == N) rowptr[s * np1 + N] = E;
}

// ---------------------------------------------------------------------------
// CSR SpMM, quarter/eighth-wave edge parallelism (round 21, unchanged).
// ---------------------------------------------------------------------------
template<int KCH, int MODE>
__global__ __launch_bounds__(256)
void spmm2_kernel(const int* __restrict__ rpR, const int* __restrict__ rpP,
                  int np1R, int np1P,
                  const int2* __restrict__ evRg, const int2* __restrict__ evPg,
                  const u16* __restrict__ InR, const u16* __restrict__ InP, int ldi,
                  u16* __restrict__ BaseR, u16* __restrict__ BaseP, int ldb,
                  u16* __restrict__ OHR, u16* __restrict__ OHP,
                  float* __restrict__ OFR, float* __restrict__ OFP, int ldo,
                  int NR, int E)
{
    int r = blockIdx.x;
    const int s    = threadIdx.x >> 6;
    const int lane = threadIdx.x & 63;
    const int* rp; const int2* ev; const u16* In; u16* Base; int np1;
    u16* OH; float* OF;
    if (r < NR) { rp = rpR; ev = evRg; In = InR; Base = BaseR; np1 = np1R;
                  OH = OHR; OF = OFR; }
    else { r -= NR; rp = rpP; ev = evPg; In = InP; Base = BaseP; np1 = np1P;
           OH = OHP; OF = OFP; }
    int e0 = __builtin_amdgcn_readfirstlane(rp[s * np1 + r]);
    int e1 = __builtin_amdgcn_readfirstlane(rp[s * np1 + r + 1]);
    if (MODE == 0 && e0 == e1) return;
    ev += (size_t)s * E;

    if (KCH == 128) {
        const int qg = lane >> 4;
        const int ql = lane & 15;
        const int col = s * 128 + ql * 8;
        float a[8] = {0.f, 0.f, 0.f, 0.f, 0.f, 0.f, 0.f, 0.f};
        int e = e0;
        for (; e + 15 < e1; e += 16) {
            int2 p0 = ev[e + qg];
            int2 p1 = ev[e + 4 + qg];
            int2 p2 = ev[e + 8 + qg];
            int2 p3 = ev[e + 12 + qg];
            float v0 = __int_as_float(p0.y), v1 = __int_as_float(p1.y);
            float v2 = __int_as_float(p2.y), v3 = __int_as_float(p3.y);
            u16x8 x0 = *(const u16x8*)(In + (size_t)p0.x * ldi + col);
            u16x8 x1 = *(const u16x8*)(In + (size_t)p1.x * ldi + col);
            u16x8 x2 = *(const u16x8*)(In + (size_t)p2.x * ldi + col);
            u16x8 x3 = *(const u16x8*)(In + (size_t)p3.x * ldi + col);
            #pragma unroll
            for (int j = 0; j < 8; ++j)
                a[j] += v0 * bf2f(x0[j]) + v1 * bf2f(x1[j])
                      + v2 * bf2f(x2[j]) + v3 * bf2f(x3[j]);
        }
        for (; e + 7 < e1; e += 8) {
            int2 p0 = ev[e + qg];
            int2 p1 = ev[e + 4 + qg];
            float v0 = __int_as_float(p0.y);
            float v1 = __int_as_float(p1.y);
            u16x8 x0 = *(const u16x8*)(In + (size_t)p0.x * ldi + col);
            u16x8 x1 = *(const u16x8*)(In + (size_t)p1.x * ldi + col);
            #pragma unroll
            for (int j = 0; j < 8; ++j)
                a[j] += v0 * bf2f(x0[j]) + v1 * bf2f(x1[j]);
        }
        for (; e < e1; e += 4) {
            if (e + qg < e1) {
                int2 pv = ev[e + qg];
                float v = __int_as_float(pv.y);
                u16x8 x = *(const u16x8*)(In + (size_t)pv.x * ldi + col);
                #pragma unroll
                for (int j = 0; j < 8; ++j)
                    a[j] += v * bf2f(x[j]);
            }
        }
        #pragma unroll
        for (int j = 0; j < 8; ++j) {
            a[j] += __shfl_xor(a[j], 16);
            a[j] += __shfl_xor(a[j], 32);
        }
        if (lane < 16) {
            u16x8* bp = (u16x8*)(Base + (size_t)r * ldb + col);
            u16x8 b = *bp;
            if (MODE == 0) {
                u16x8 nb;
                #pragma unroll
                for (int j = 0; j < 8; ++j) nb[j] = f2bf(bf2f(b[j]) + a[j]);
                *bp = nb;
            } else if (MODE == 1) {
                u16x8 h;
                #pragma unroll
                for (int j = 0; j < 8; ++j) h[j] = f2bf(fmaxf(bf2f(b[j]) + a[j], 0.f));
                *(u16x8*)(OH + (size_t)r * ldo + col) = h;
            } else {
                f32x4 o0, o1;
                #pragma unroll
                for (int j = 0; j < 4; ++j) {
                    o0[j] = fmaxf(bf2f(b[j]) + a[j], 0.f);
                    o1[j] = fmaxf(bf2f(b[4 + j]) + a[4 + j], 0.f);
                }
                *(f32x4*)(OF + (size_t)r * ldo + col) = o0;
                *(f32x4*)(OF + (size_t)r * ldo + col + 4) = o1;
            }
        }
    } else {   // KCH == 64
        const int og = lane >> 3;
        const int ol = lane & 7;
        const int col = s * 64 + ol * 8;
        float a[8] = {0.f, 0.f, 0.f, 0.f, 0.f, 0.f, 0.f, 0.f};
        int e = e0;
        for (; e + 15 < e1; e += 16) {
            int2 p0 = ev[e + og];
            int2 p1 = ev[e + 8 + og];
            float v0 = __int_as_float(p0.y);
            float v1 = __int_as_float(p1.y);
            u16x8 x0 = *(const u16x8*)(In + (size_t)p0.x * ldi + col);
            u16x8 x1 = *(const u16x8*)(In + (size_t)p1.x * ldi + col);
            #pragma unroll
            for (int j = 0; j < 8; ++j)
                a[j] += v0 * bf2f(x0[j]) + v1 * bf2f(x1[j]);
        }
        for (; e < e1; e += 8) {
            if (e + og < e1) {
                int2 pv = ev[e + og];
                float v = __int_as_float(pv.y);
                u16x8 x = *(const u16x8*)(In + (size_t)pv.x * ldi + col);
                #pragma unroll
                for (int j = 0; j < 8; ++j)
                    a[j] += v * bf2f(x[j]);
            }
        }
        #pragma unroll
        for (int j = 0; j < 8; ++j) {
            a[j] += __shfl_xor(a[j], 8);
            a[j] += __shfl_xor(a[j], 16);
            a[j] += __shfl_xor(a[j], 32);
        }
        if (lane < 8) {
            u16x8* bp = (u16x8*)(Base + (size_t)r * ldb + col);
            u16x8 b = *bp;
            if (MODE == 0) {
                u16x8 nb;
                #pragma unroll
                for (int j = 0; j < 8; ++j) nb[j] = f2bf(bf2f(b[j]) + a[j]);
                *bp = nb;
            } else {
                f32x4 o0, o1;
                #pragma unroll
                for (int j = 0; j < 4; ++j) {
                    o0[j] = fmaxf(bf2f(b[j]) + a[j], 0.f);
                    o1[j] = fmaxf(bf2f(b[4 + j]) + a[4 + j], 0.f);
                }
                *(f32x4*)(OF + (size_t)r * ldo + col) = o0;
                *(f32x4*)(OF + (size_t)r * ldo + col + 4) = o1;
            }
        }
    }
}

// fallback-only final relu over bf16 base
__global__ __launch_bounds__(256)
void relu_out_kernel(const u16* __restrict__ Z, int ld, int coff,
                     float* __restrict__ out, int M)
{
    int g = blockIdx.x * 256 + threadIdx.x;
    if (g >= M * 256) return;
    int row = g >> 8;
    int col = g & 255;
    out[g] = fmaxf(bf2f(Z[(size_t)row * ld + coff + col]), 0.f);
}

// ---------------------------------------------------------------------------
// weight packing (transposed [N][K], bf16)
// ---------------------------------------------------------------------------
__global__ __launch_bounds__(256)
void pack_b0_kernel(const float* __restrict__ w0, const float* __restrict__ sw0,
                    u16* __restrict__ Bh)
{
    int g = blockIdx.x * 256 + threadIdx.x;
    int j = g >> 10, d = g & 1023;
    float v;
    if (j < 512) v = w0[((size_t)(j >> 7) * 1024 + d) * 128 + (j & 127)];
    else         v = sw0[(size_t)d * 512 + (j - 512)];
    Bh[g] = f2bf(v);
}

__global__ __launch_bounds__(256)
void pack_b1_kernel(const float* __restrict__ w1, const float* __restrict__ sw1,
                    u16* __restrict__ Bh)
{
    int g = blockIdx.x * 256 + threadIdx.x;
    int j = g >> 9, d = g & 511;
    float v;
    if (j < 256) v = w1[((size_t)(j >> 6) * 512 + d) * 64 + (j & 63)];
    else         v = sw1[(size_t)d * 256 + (j - 256)];
    Bh[g] = f2bf(v);
}

extern "C" void kernel_launch(void* const* d_in, const int* in_sizes, int n_in,
                              void* d_out, int out_size, void* d_ws, size_t ws_size,
                              hipStream_t stream)
{
    const int*   rna_rows  = (const int*)  d_in[0];
    const int*   rna_cols  = (const int*)  d_in[1];
    const float* rna_vals  = (const float*)d_in[2];
    const int*   prot_rows = (const int*)  d_in[3];
    const int*   prot_cols = (const int*)  d_in[4];
    const float* prot_vals = (const float*)d_in[5];
    const float* H_rna     = (const float*)d_in[6];
    const float* H_prot    = (const float*)d_in[7];
    const float* w0        = (const float*)d_in[8];
    const float* sw0       = (const float*)d_in[9];
    const float* w1        = (const float*)d_in[10];
    const float* sw1       = (const float*)d_in[11];

    const int NRNA = 50000, NPROT = 20000, S = 4, E = 500000;
    const int MP_RNA = 50048, MP_PROT = 20096;
    const int MP_ALL = MP_RNA + MP_PROT;           // 70144 = 274 * 256
    const int NP1_R = NRNA + 1, NP1_P = NPROT + 1;
    const int NB_R = (NRNA + 255) / 256;
    const int NB_P = (NPROT + 255) / 256;
    const int EB4  = (E + 1023) / 1024;
    const int EB16 = (E + 4095) / 4096;
    const int FX16 = EB16 * 8;

    // --- ws layout ---
    char* ws = (char*)d_ws;
    size_t off = 0;
    u16*   Y16   = (u16*)  (ws + off); off += (size_t)MP_ALL * 1024 * 2;  // L0 [*,1024]; L1 aliases [*,512]
    u16*   Ahbig = (u16*)  (ws + off); off += (size_t)MP_ALL * 1024 * 2;
    u16*   B0h   = (u16*)  (ws + off); off += (size_t)1024 * 1024 * 2;
    u16*   B1h   = (u16*)  (ws + off); off += (size_t)512 * 512 * 2;
    size_t base_bytes = off;

    u16* AhR = Ahbig;                               // layer-1 A views [MP_ALL][512]
    u16* AhP = Ahbig + (size_t)MP_RNA * 512;

    // CSR scratch (ev + packed rows + meta)
    size_t csr_bytes = 0;
    csr_bytes += (size_t)S * E * 8 * 2;                       // evR + evP
    csr_bytes += (size_t)S * E * 2 * 2;                       // r16R + r16P
    csr_bytes += ((size_t)S * (NRNA * 2 + NP1_R + NB_R)) * 4;
    csr_bytes += ((size_t)S * (NPROT * 2 + NP1_P + NB_P)) * 4;
    const bool csr_in_ws = (ws_size >= base_bytes + csr_bytes);

    char* csr = csr_in_ws ? (ws + base_bytes) : (char*)d_out;
    size_t coff = 0;
    int2*  evR     = (int2*) (csr + coff); coff += (size_t)S * E * 8;
    int2*  evP     = (int2*) (csr + coff); coff += (size_t)S * E * 8;
    u16*   r16R    = (u16*)  (csr + coff); coff += (size_t)S * E * 2;
    u16*   r16P    = (u16*)  (csr + coff); coff += (size_t)S * E * 2;
    int*   countsR = (int*)  (csr + coff); coff += (size_t)S * NRNA * 4;
    int*   rowptrR = (int*)  (csr + coff); coff += (size_t)S * NP1_R * 4;
    int*   cursorR = (int*)  (csr + coff); coff += (size_t)S * NRNA * 4;
    int*   bsumR   = (int*)  (csr + coff); coff += (size_t)S * NB_R * 4;
    int*   countsP = (int*)  (csr + coff); coff += (size_t)S * NPROT * 4;
    int*   rowptrP = (int*)  (csr + coff); coff += (size_t)S * NP1_P * 4;
    int*   cursorP = (int*)  (csr + coff); coff += (size_t)S * NPROT * 4;
    int*   bsumP   = (int*)  (csr + coff); coff += (size_t)S * NB_P * 4;

    dim3 blk(256);
    float* out = (float*)d_out;

    // --- pack weights ---
    pack_b0_kernel<<<(1024 * 1024) / 256, blk, 0, stream>>>(w0, sw0, B0h);
    pack_b1_kernel<<<(512 * 512) / 256, blk, 0, stream>>>(w1, sw1, B1h);

    // --- CSR build prefix (pack+hist merged) ---
    zero2_i32_kernel<<<(S * NRNA + 255) / 256, blk, 0, stream>>>(countsR, S * NRNA,
                                                                 countsP, S * NPROT);
    pack_hist2_kernel<<<dim3(EB4, S, 2), blk, 0, stream>>>(
        rna_rows, prot_rows, r16R, r16P, countsR, countsP, NRNA, NPROT, E);
    scan_block2_kernel<<<dim3(NB_R, S, 2), blk, 0, stream>>>(
        countsR, rowptrR, bsumR, NRNA, NP1_R, NB_R,
        countsP, rowptrP, bsumP, NPROT, NP1_P, NB_P);
    scan_aux2_kernel<<<8, blk, 0, stream>>>(bsumR, NB_R, bsumP, NB_P);
    finalize2_kernel<<<dim3(NB_R, S, 2), blk, 0, stream>>>(
        rowptrR, bsumR, cursorR, NRNA, NP1_R, NB_R,
        rowptrP, bsumP, cursorP, NPROT, NP1_P, NB_P, E);

    // --- fill (standalone, 16 edges/thread) ---
    fill16_kernel<<<dim3(FX16, S, 2), blk, 0, stream>>>(
        r16R, rna_cols, rna_vals, r16P, prot_cols, prot_vals,
        cursorR, cursorP, evR, evP, NRNA, NPROT, E);

    // --- cvt (standalone) ---
    cvt_bf16_kernel<<<MP_RNA / 2, blk, 0, stream>>>(H_rna, Ahbig, NRNA);
    cvt_bf16_kernel<<<MP_PROT / 2, blk, 0, stream>>>(H_prot, Ahbig + (size_t)MP_RNA * 1024,
                                                     NPROT);

    // --- layer 0 GEMM (256x128 tile: 8 N-blocks, 274 M-blocks) ---
    gemm_bf16_kernel<<<8 * (MP_ALL / 256), blk, 0, stream>>>(
        Ahbig, B0h, Y16, 1024, 1024, 7, 3);

    // --- layer 0 SpMM: Ah = bf16(relu(base + agg)) ---
    spmm2_kernel<128, 1><<<NRNA + NPROT, blk, 0, stream>>>(
        rowptrR, rowptrP, NP1_R, NP1_P, evR, evP,
        Y16 + (size_t)MP_RNA * 1024,      // RNA gathers prot tmp (cols 0..511)
        Y16,                              // PROT gathers rna tmp
        1024,
        Y16 + 512, Y16 + (size_t)MP_RNA * 1024 + 512, 1024,   // bf16 base halves
        AhR, AhP, nullptr, nullptr, 512,
        NRNA, E);

    // --- zero layer-1 A pad rows ---
    zero_u16_kernel<<<(48 * 512 + 255) / 256, blk, 0, stream>>>(
        AhR + (size_t)NRNA * 512, 48 * 512);
    zero_u16_kernel<<<(96 * 512 + 255) / 256, blk, 0, stream>>>(
        AhP + (size_t)NPROT * 512, 96 * 512);

    // --- layer 1: GEMM (N=512 -> 4 N-blocks, K=512) ---
    gemm_bf16_kernel<<<4 * (MP_ALL / 256), blk, 0, stream>>>(
        Ahbig, B1h, Y16, 512, 512, 3, 2);

    // --- layer 1 SpMM ---
    if (csr_in_ws) {
        spmm2_kernel<64, 2><<<NRNA + NPROT, blk, 0, stream>>>(
            rowptrR, rowptrP, NP1_R, NP1_P, evR, evP,
            Y16 + (size_t)MP_RNA * 512, Y16, 512,
            Y16 + 256, Y16 + (size_t)MP_RNA * 512 + 256, 512,
            nullptr, nullptr,
            out, out + (size_t)NRNA * 256, 256,
            NRNA, E);
    } else {
        spmm2_kernel<64, 0><<<NRNA + NPROT, blk, 0, stream>>>(
            rowptrR, rowptrP, NP1_R, NP1_P, evR, evP,
            Y16 + (size_t)MP_RNA * 512, Y16, 512,
            Y16 + 256, Y16 + (size_t)MP_RNA * 512 + 256, 512,
            nullptr, nullptr,
            nullptr, nullptr, 0,
            NRNA, E);
        relu_out_kernel<<<(NRNA * 256) / 256, blk, 0, stream>>>(Y16, 512, 256, out, NRNA);
        relu_out_kernel<<<(NPROT * 256) / 256, blk, 0, stream>>>(
            Y16 + (size_t)MP_RNA * 512, 512, 256, out + (size_t)NRNA * 256, NPROT);
    }
}

// Round 23
// 963.796 us; speedup vs baseline: 1.0929x; 1.0929x over previous
//
#include <hip/hip_runtime.h>
#include <hip/hip_bf16.h>

// ---------------------------------------------------------------------------
// StackGCNEncoder on MI355X — round 23 (= exact round-20 revert, measured best
// 962 us):
//   r22 post-mortem: 256x128 GEMM retile regressed (VGPR 132 -> occupancy 10%).
//   128x128/4-wave GEMM confirmed as structure optimum (3rd tile experiment).
//   Config: fused cvt∥fill16, pack_hist merged, quarter/eighth-wave spmm
//   (unroll-2), all-bf16 Y, 1-term GEMM, counted vmcnt, XOR+XCD swizzles.
// ---------------------------------------------------------------------------

typedef unsigned short u16;
typedef short s16x8 __attribute__((ext_vector_type(8)));
typedef float f32x4 __attribute__((ext_vector_type(4)));
typedef __attribute__((ext_vector_type(8))) unsigned short u16x8;
typedef unsigned long long u64;

__device__ __forceinline__ u16 f2bf(float x) {            // RNE f32->bf16
    unsigned u = __float_as_uint(x);
    return (u16)((u + 0x7fff + ((u >> 16) & 1)) >> 16);
}
__device__ __forceinline__ float bf2f(u16 h) {
    return __uint_as_float(((unsigned)h) << 16);
}

__device__ __forceinline__ void gload16(const u16* g, u16* l) {
    __builtin_amdgcn_global_load_lds(
        (const __attribute__((address_space(1))) unsigned int*)g,
        (__attribute__((address_space(3))) unsigned int*)l,
        16, 0, 0);
}

// ---------------------------------------------------------------------------
// bf16 GEMM (r18/r20 form): Y16 = A x B^T, all-bf16 out. 128x128, BK=32.
// ---------------------------------------------------------------------------
__global__ __launch_bounds__(256)
void gemm_bf16_kernel(const u16* __restrict__ Ah, const u16* __restrict__ Bh,
                      u16* __restrict__ Y, int ldy,
                      int K, int nxmask, int nxshift)
{
    __shared__ u16 lds[2][2][4096];   // 32 KB

    const int nwg = gridDim.x;
    const int q   = nwg >> 3, r8 = nwg & 7;
    const int xcd = blockIdx.x & 7, pos = blockIdx.x >> 3;
    const int lin = (xcd < r8 ? xcd * (q + 1) : r8 * (q + 1) + (xcd - r8) * q) + pos;
    const int bm0 = (lin >> nxshift) * 128;
    const int bn0 = (lin & nxmask) * 128;

    const int tid  = threadIdx.x;
    const int lane = tid & 63;
    const int wid  = tid >> 6;
    const int wr   = wid >> 1;
    const int wc   = wid & 1;

    const int srow = tid >> 2;
    const int scol = ((tid & 3) ^ ((tid >> 3) & 3)) * 8;   // u16 units
    const size_t aoff0 = (size_t)(bm0 + srow) * K + scol;
    const size_t aoff1 = (size_t)(bm0 + srow + 64) * K + scol;
    const size_t boff0 = (size_t)(bn0 + srow) * K + scol;
    const size_t boff1 = (size_t)(bn0 + srow + 64) * K + scol;
    const int c0 = tid * 8;
    const int c1 = 2048 + tid * 8;

    u16* L0 = &lds[0][0][0];              // buffer stride 8192 u16

    f32x4 zero = {0.f, 0.f, 0.f, 0.f};
    f32x4 acc[4][4];
    #pragma unroll
    for (int i = 0; i < 4; ++i)
        #pragma unroll
        for (int j = 0; j < 4; ++j) acc[i][j] = zero;

    const int fchunk = (((lane >> 4) ^ ((lane >> 1) & 3))) * 8;
    const int a_fr = (wr * 64 + (lane & 15)) * 32 + fchunk;
    const int b_fr = (wc * 64 + (lane & 15)) * 32 + fchunk;

    const int nk = K >> 5;

    {
        u16* L = L0;
        gload16(Ah + aoff0, L + c0);          gload16(Ah + aoff1, L + c1);
        gload16(Bh + boff0, L + 4096 + c0);   gload16(Bh + boff1, L + 4096 + c1);
    }
    int cur = 0;
    for (int t = 0; t < nk; ++t) {
        if (t + 1 < nk) {
            const int k0 = (t + 1) * 32;
            u16* L = L0 + (cur ^ 1) * 8192;
            gload16(Ah + aoff0 + k0, L + c0);         gload16(Ah + aoff1 + k0, L + c1);
            gload16(Bh + boff0 + k0, L + 4096 + c0);  gload16(Bh + boff1 + k0, L + 4096 + c1);
            asm volatile("s_waitcnt vmcnt(4)\n\ts_barrier" ::: "memory");
        } else {
            asm volatile("s_waitcnt vmcnt(0)\n\ts_barrier" ::: "memory");
        }
        const u16* L = L0 + cur * 8192;
        s16x8 bh[4];
        #pragma unroll
        for (int nf = 0; nf < 4; ++nf)
            bh[nf] = *(const s16x8*)(L + 4096 + b_fr + nf * 512);
        #pragma unroll
        for (int mf = 0; mf < 4; ++mf) {
            s16x8 ahv = *(const s16x8*)(L + a_fr + mf * 512);
            #pragma unroll
            for (int nf = 0; nf < 4; ++nf)
                acc[mf][nf] = __builtin_amdgcn_mfma_f32_16x16x32_bf16(ahv, bh[nf], acc[mf][nf], 0, 0, 0);
        }
        asm volatile("s_barrier" ::: "memory");
        cur ^= 1;
    }

    #pragma unroll
    for (int mf = 0; mf < 4; ++mf) {
        const int row0 = bm0 + wr * 64 + mf * 16 + (lane >> 4) * 4;
        #pragma unroll
        for (int nf = 0; nf < 4; ++nf) {
            const int col = bn0 + wc * 64 + nf * 16 + (lane & 15);
            #pragma unroll
            for (int r = 0; r < 4; ++r)
                Y[(size_t)(row0 + r) * ldy + col] = f2bf(acc[mf][nf][r]);
        }
    }
}

// ---------------------------------------------------------------------------
// cvt body: f32 [M][1024] -> bf16 (8 elems/thread), zero-padded rows.
// ---------------------------------------------------------------------------
__device__ __forceinline__
void cvt_body(int bid, const float* __restrict__ A, u16* __restrict__ Hh, int M)
{
    const size_t g  = (size_t)bid * 256 + threadIdx.x;
    const size_t i8 = g * 8;
    const int row   = (int)(i8 >> 10);
    f32x4 a = {0.f, 0.f, 0.f, 0.f}, b = {0.f, 0.f, 0.f, 0.f};
    if (row < M) {
        a = *(const f32x4*)(A + i8);
        b = *(const f32x4*)(A + i8 + 4);
    }
    u16x8 h;
    #pragma unroll
    for (int j = 0; j < 4; ++j) { h[j] = f2bf(a[j]); h[4 + j] = f2bf(b[j]); }
    *(u16x8*)(Hh + i8) = h;
}

// ---------------------------------------------------------------------------
// fill body: 16 edges/thread, row-sliced XCD-affine, u16 rows.
// ---------------------------------------------------------------------------
__device__ __forceinline__
void fill_body16(int fx, int s, int side,
                 const u16* __restrict__ r16R, const int* __restrict__ colsR,
                 const float* __restrict__ valsR,
                 const u16* __restrict__ r16P, const int* __restrict__ colsP,
                 const float* __restrict__ valsP,
                 int* __restrict__ curR, int* __restrict__ curP,
                 int2* __restrict__ evR, int2* __restrict__ evP,
                 int NR, int NP, int E)
{
    const int slice = fx & 7;
    const int chunk = fx >> 3;
    const int N          = side ? NP : NR;
    const u16* r16       = side ? r16P : r16R;
    const int* cols      = side ? colsP : colsR;
    const float* vals    = side ? valsP : valsR;
    int* cursor          = side ? curP : curR;
    int2* ev             = side ? evP : evR;

    const int Nsl = (N + 7) >> 3;
    const int r0 = slice * Nsl;
    const int r1 = min(N, r0 + Nsl);

    const int e0 = chunk * 4096 + threadIdx.x * 16;
    if (e0 >= E) return;
    const size_t base = (size_t)s * E;

    if (e0 + 16 <= E) {
        u64 rq[4];
        #pragma unroll
        for (int g = 0; g < 4; ++g)
            rq[g] = *(const u64*)(r16 + base + e0 + g * 4);
        #pragma unroll
        for (int g = 0; g < 4; ++g) {
            #pragma unroll
            for (int j = 0; j < 4; ++j) {
                int r = (int)(u16)(rq[g] >> (16 * j));
                if (r >= r0 && r < r1) {
                    int idx = e0 + g * 4 + j;
                    int pos = atomicAdd(cursor + s * N + r, 1);
                    ev[base + pos] = make_int2(cols[base + idx],
                                               __float_as_int(vals[base + idx]));
                }
            }
        }
    } else {
        for (int j = 0; j < 16 && e0 + j < E; ++j) {
            int r = (int)r16[base + e0 + j];
            if (r >= r0 && r < r1) {
                int pos = atomicAdd(cursor + s * N + r, 1);
                ev[base + pos] = make_int2(cols[base + e0 + j],
                                           __float_as_int(vals[base + e0 + j]));
            }
        }
    }
}

// ---------------------------------------------------------------------------
// FUSED cvt ∥ fill: grid (XW, 4, 3). z==0 -> cvt (id = y*XW+x);
// z in {1,2} -> fill side z-1, s=y, fx=x (x < FX16). No LDS -> 8 blocks/CU.
// ---------------------------------------------------------------------------
__global__ __launch_bounds__(256)
void fused_cvt_fill_kernel(const float* __restrict__ H_rna, const float* __restrict__ H_prot,
                           u16* __restrict__ AhR_full, u16* __restrict__ AhP_full,
                           int CVR, int CV, int XW,
                           const u16* __restrict__ r16R, const int* __restrict__ colsR,
                           const float* __restrict__ valsR,
                           const u16* __restrict__ r16P, const int* __restrict__ colsP,
                           const float* __restrict__ valsP,
                           int* __restrict__ curR, int* __restrict__ curP,
                           int2* __restrict__ evR, int2* __restrict__ evP,
                           int NR, int NP, int E, int FX16)
{
    const int z = blockIdx.z;
    if (z == 0) {
        int id = blockIdx.y * XW + blockIdx.x;
        if (id >= CV) return;
        if (id < CVR) cvt_body(id, H_rna, AhR_full, NR);
        else          cvt_body(id - CVR, H_prot, AhP_full, NP);
    } else {
        if ((int)blockIdx.x >= FX16) return;
        fill_body16(blockIdx.x, blockIdx.y, z - 1,
                    r16R, colsR, valsR, r16P, colsP, valsP,
                    curR, curP, evR, evP, NR, NP, E);
    }
}

__global__ __launch_bounds__(256)
void zero_u16_kernel(u16* __restrict__ a, int n)
{
    int i = blockIdx.x * 256 + threadIdx.x;
    if (i < n) a[i] = 0;
}

// ---------------------------------------------------------------------------
// CSR build
// ---------------------------------------------------------------------------
__global__ __launch_bounds__(256)
void zero2_i32_kernel(int* __restrict__ a, int na, int* __restrict__ b, int nb)
{
    int i = blockIdx.x * 256 + threadIdx.x;
    if (i < na) a[i] = 0;
    if (i < nb) b[i] = 0;
}

// merged: pack rows int32 -> u16 AND histogram, one read pass. 4 edges/thread.
__global__ __launch_bounds__(256)
void pack_hist2_kernel(const int* __restrict__ rowsR, const int* __restrict__ rowsP,
                       u16* __restrict__ r16R, u16* __restrict__ r16P,
                       int* __restrict__ cntR, int* __restrict__ cntP,
                       int NR, int NP, int E)
{
    int s = blockIdx.y;
    int e = (blockIdx.x * 256 + threadIdx.x) * 4;
    if (e >= E) return;
    const int* rows = blockIdx.z ? rowsP : rowsR;
    u16* r16 = blockIdx.z ? r16P : r16R;
    int* cnt = blockIdx.z ? cntP : cntR;
    const int N = blockIdx.z ? NP : NR;
    size_t base = (size_t)s * E;
    if (e + 4 <= E) {
        int4 r4 = *(const int4*)(rows + base + e);
        u16 p[4] = {(u16)r4.x, (u16)r4.y, (u16)r4.z, (u16)r4.w};
        *(u64*)(r16 + base + e) = *(const u64*)p;
        atomicAdd(cnt + s * N + r4.x, 1);
        atomicAdd(cnt + s * N + r4.y, 1);
        atomicAdd(cnt + s * N + r4.z, 1);
        atomicAdd(cnt + s * N + r4.w, 1);
    } else {
        for (int j = 0; j < 4 && e + j < E; ++j) {
            int r = rows[base + e + j];
            r16[base + e + j] = (u16)r;
            atomicAdd(cnt + s * N + r, 1);
        }
    }
}

__global__ __launch_bounds__(256)
void scan_block2_kernel(const int* __restrict__ cR, int* __restrict__ rpR,
                        int* __restrict__ bsR, int NR, int np1R, int NBR,
                        const int* __restrict__ cP, int* __restrict__ rpP,
                        int* __restrict__ bsP, int NP, int np1P, int NBP)
{
    const int side = blockIdx.z;
    const int NB = side ? NBP : NBR;
    if ((int)blockIdx.x >= NB) return;
    const int N = side ? NP : NR;
    const int np1 = side ? np1P : np1R;
    const int* counts = side ? cP : cR;
    int* rowptr = side ? rpP : rpR;
    int* blocksum = side ? bsP : bsR;

    __shared__ int sd[256];
    int s = blockIdx.y;
    int i = blockIdx.x * 256 + threadIdx.x;
    int tid = threadIdx.x;
    int v = (i < N) ? counts[s * N + i] : 0;
    sd[tid] = v;
    __syncthreads();
    #pragma unroll
    for (int off = 1; off < 256; off <<= 1) {
        int t = (tid >= off) ? sd[tid - off] : 0;
        __syncthreads();
        sd[tid] += t;
        __syncthreads();
    }
    if (i < N) rowptr[s * np1 + i] = sd[tid] - v;
    if (tid == 255) blocksum[s * NB + blockIdx.x] = sd[255];
}

__global__ __launch_bounds__(256)
void scan_aux2_kernel(int* __restrict__ bsR, int NBR, int* __restrict__ bsP, int NBP)
{
    const int side = blockIdx.x >> 2;
    const int s = blockIdx.x & 3;
    int* blocksum = side ? bsP : bsR;
    const int NB = side ? NBP : NBR;

    __shared__ int sd[256];
    int tid = threadIdx.x;
    int v = (tid < NB) ? blocksum[s * NB + tid] : 0;
    sd[tid] = v;
    __syncthreads();
    #pragma unroll
    for (int off = 1; off < 256; off <<= 1) {
        int t = (tid >= off) ? sd[tid - off] : 0;
        __syncthreads();
        sd[tid] += t;
        __syncthreads();
    }
    if (tid < NB) blocksum[s * NB + tid] = sd[tid] - v;
}

__global__ __launch_bounds__(256)
void finalize2_kernel(int* __restrict__ rpR, const int* __restrict__ bsR,
                      int* __restrict__ curR, int NR, int np1R, int NBR,
                      int* __restrict__ rpP, const int* __restrict__ bsP,
                      int* __restrict__ curP, int NP, int np1P, int NBP, int E)
{
    const int side = blockIdx.z;
    const int NB = side ? NBP : NBR;
    if ((int)blockIdx.x >= NB) return;
    const int N = side ? NP : NR;
    const int np1 = side ? np1P : np1R;
    int* rowptr = side ? rpP : rpR;
    const int* blocksum = side ? bsP : bsR;
    int* cursor = side ? curP : curR;

    int s = blockIdx.y;
    int i = blockIdx.x * 256 + threadIdx.x;
    if (i < N) {
        int v = rowptr[s * np1 + i] + blocksum[s * NB + blockIdx.x];
        rowptr[s * np1 + i] = v;
        cursor[s * N + i] = v;
    }
    if (i == N) rowptr[s * np1 + N] = E;
}

// ---------------------------------------------------------------------------
// CSR SpMM, quarter/eighth-wave edge parallelism (r17/r20 form, unroll-2).
// ---------------------------------------------------------------------------
template<int KCH, int MODE>
__global__ __launch_bounds__(256)
void spmm2_kernel(const int* __restrict__ rpR, const int* __restrict__ rpP,
                  int np1R, int np1P,
                  const int2* __restrict__ evRg, const int2* __restrict__ evPg,
                  const u16* __restrict__ InR, const u16* __restrict__ InP, int ldi,
                  u16* __restrict__ BaseR, u16* __restrict__ BaseP, int ldb,
                  u16* __restrict__ OHR, u16* __restrict__ OHP,
                  float* __restrict__ OFR, float* __restrict__ OFP, int ldo,
                  int NR, int E)
{
    int r = blockIdx.x;
    const int s    = threadIdx.x >> 6;
    const int lane = threadIdx.x & 63;
    const int* rp; const int2* ev; const u16* In; u16* Base; int np1;
    u16* OH; float* OF;
    if (r < NR) { rp = rpR; ev = evRg; In = InR; Base = BaseR; np1 = np1R;
                  OH = OHR; OF = OFR; }
    else { r -= NR; rp = rpP; ev = evPg; In = InP; Base = BaseP; np1 = np1P;
           OH = OHP; OF = OFP; }
    int e0 = __builtin_amdgcn_readfirstlane(rp[s * np1 + r]);
    int e1 = __builtin_amdgcn_readfirstlane(rp[s * np1 + r + 1]);
    if (MODE == 0 && e0 == e1) return;
    ev += (size_t)s * E;

    if (KCH == 128) {
        const int qg = lane >> 4;
        const int ql = lane & 15;
        const int col = s * 128 + ql * 8;
        float a[8] = {0.f, 0.f, 0.f, 0.f, 0.f, 0.f, 0.f, 0.f};
        int e = e0;
        for (; e + 7 < e1; e += 8) {
            int2 p0 = ev[e + qg];
            int2 p1 = ev[e + 4 + qg];
            float v0 = __int_as_float(p0.y);
            float v1 = __int_as_float(p1.y);
            u16x8 x0 = *(const u16x8*)(In + (size_t)p0.x * ldi + col);
            u16x8 x1 = *(const u16x8*)(In + (size_t)p1.x * ldi + col);
            #pragma unroll
            for (int j = 0; j < 8; ++j)
                a[j] += v0 * bf2f(x0[j]) + v1 * bf2f(x1[j]);
        }
        for (; e < e1; e += 4) {
            if (e + qg < e1) {
                int2 pv = ev[e + qg];
                float v = __int_as_float(pv.y);
                u16x8 x = *(const u16x8*)(In + (size_t)pv.x * ldi + col);
                #pragma unroll
                for (int j = 0; j < 8; ++j)
                    a[j] += v * bf2f(x[j]);
            }
        }
        #pragma unroll
        for (int j = 0; j < 8; ++j) {
            a[j] += __shfl_xor(a[j], 16);
            a[j] += __shfl_xor(a[j], 32);
        }
        if (lane < 16) {
            u16x8* bp = (u16x8*)(Base + (size_t)r * ldb + col);
            u16x8 b = *bp;
            if (MODE == 0) {
                u16x8 nb;
                #pragma unroll
                for (int j = 0; j < 8; ++j) nb[j] = f2bf(bf2f(b[j]) + a[j]);
                *bp = nb;
            } else if (MODE == 1) {
                u16x8 h;
                #pragma unroll
                for (int j = 0; j < 8; ++j) h[j] = f2bf(fmaxf(bf2f(b[j]) + a[j], 0.f));
                *(u16x8*)(OH + (size_t)r * ldo + col) = h;
            } else {
                f32x4 o0, o1;
                #pragma unroll
                for (int j = 0; j < 4; ++j) {
                    o0[j] = fmaxf(bf2f(b[j]) + a[j], 0.f);
                    o1[j] = fmaxf(bf2f(b[4 + j]) + a[4 + j], 0.f);
                }
                *(f32x4*)(OF + (size_t)r * ldo + col) = o0;
                *(f32x4*)(OF + (size_t)r * ldo + col + 4) = o1;
            }
        }
    } else {   // KCH == 64
        const int og = lane >> 3;
        const int ol = lane & 7;
        const int col = s * 64 + ol * 8;
        float a[8] = {0.f, 0.f, 0.f, 0.f, 0.f, 0.f, 0.f, 0.f};
        int e = e0;
        for (; e + 15 < e1; e += 16) {
            int2 p0 = ev[e + og];
            int2 p1 = ev[e + 8 + og];
            float v0 = __int_as_float(p0.y);
            float v1 = __int_as_float(p1.y);
            u16x8 x0 = *(const u16x8*)(In + (size_t)p0.x * ldi + col);
            u16x8 x1 = *(const u16x8*)(In + (size_t)p1.x * ldi + col);
            #pragma unroll
            for (int j = 0; j < 8; ++j)
                a[j] += v0 * bf2f(x0[j]) + v1 * bf2f(x1[j]);
        }
        for (; e < e1; e += 8) {
            if (e + og < e1) {
                int2 pv = ev[e + og];
                float v = __int_as_float(pv.y);
                u16x8 x = *(const u16x8*)(In + (size_t)pv.x * ldi + col);
                #pragma unroll
                for (int j = 0; j < 8; ++j)
                    a[j] += v * bf2f(x[j]);
            }
        }
        #pragma unroll
        for (int j = 0; j < 8; ++j) {
            a[j] += __shfl_xor(a[j], 8);
            a[j] += __shfl_xor(a[j], 16);
            a[j] += __shfl_xor(a[j], 32);
        }
        if (lane < 8) {
            u16x8* bp = (u16x8*)(Base + (size_t)r * ldb + col);
            u16x8 b = *bp;
            if (MODE == 0) {
                u16x8 nb;
                #pragma unroll
                for (int j = 0; j < 8; ++j) nb[j] = f2bf(bf2f(b[j]) + a[j]);
                *bp = nb;
            } else {
                f32x4 o0, o1;
                #pragma unroll
                for (int j = 0; j < 4; ++j) {
                    o0[j] = fmaxf(bf2f(b[j]) + a[j], 0.f);
                    o1[j] = fmaxf(bf2f(b[4 + j]) + a[4 + j], 0.f);
                }
                *(f32x4*)(OF + (size_t)r * ldo + col) = o0;
                *(f32x4*)(OF + (size_t)r * ldo + col + 4) = o1;
            }
        }
    }
}

// fallback-only final relu over bf16 base
__global__ __launch_bounds__(256)
void relu_out_kernel(const u16* __restrict__ Z, int ld, int coff,
                     float* __restrict__ out, int M)
{
    int g = blockIdx.x * 256 + threadIdx.x;
    if (g >= M * 256) return;
    int row = g >> 8;
    int col = g & 255;
    out[g] = fmaxf(bf2f(Z[(size_t)row * ld + coff + col]), 0.f);
}

// ---------------------------------------------------------------------------
// weight packing (transposed [N][K], bf16)
// ---------------------------------------------------------------------------
__global__ __launch_bounds__(256)
void pack_b0_kernel(const float* __restrict__ w0, const float* __restrict__ sw0,
                    u16* __restrict__ Bh)
{
    int g = blockIdx.x * 256 + threadIdx.x;
    int j = g >> 10, d = g & 1023;
    float v;
    if (j < 512) v = w0[((size_t)(j >> 7) * 1024 + d) * 128 + (j & 127)];
    else         v = sw0[(size_t)d * 512 + (j - 512)];
    Bh[g] = f2bf(v);
}

__global__ __launch_bounds__(256)
void pack_b1_kernel(const float* __restrict__ w1, const float* __restrict__ sw1,
                    u16* __restrict__ Bh)
{
    int g = blockIdx.x * 256 + threadIdx.x;
    int j = g >> 9, d = g & 511;
    float v;
    if (j < 256) v = w1[((size_t)(j >> 6) * 512 + d) * 64 + (j & 63)];
    else         v = sw1[(size_t)d * 256 + (j - 256)];
    Bh[g] = f2bf(v);
}

extern "C" void kernel_launch(void* const* d_in, const int* in_sizes, int n_in,
                              void* d_out, int out_size, void* d_ws, size_t ws_size,
                              hipStream_t stream)
{
    const int*   rna_rows  = (const int*)  d_in[0];
    const int*   rna_cols  = (const int*)  d_in[1];
    const float* rna_vals  = (const float*)d_in[2];
    const int*   prot_rows = (const int*)  d_in[3];
    const int*   prot_cols = (const int*)  d_in[4];
    const float* prot_vals = (const float*)d_in[5];
    const float* H_rna     = (const float*)d_in[6];
    const float* H_prot    = (const float*)d_in[7];
    const float* w0        = (const float*)d_in[8];
    const float* sw0       = (const float*)d_in[9];
    const float* w1        = (const float*)d_in[10];
    const float* sw1       = (const float*)d_in[11];

    const int NRNA = 50000, NPROT = 20000, S = 4, E = 500000;
    const int MP_RNA = 50048, MP_PROT = 20096;
    const int MP_ALL = MP_RNA + MP_PROT;           // 70144 = 548 * 128
    const int NP1_R = NRNA + 1, NP1_P = NPROT + 1;
    const int NB_R = (NRNA + 255) / 256;
    const int NB_P = (NPROT + 255) / 256;
    const int EB4  = (E + 1023) / 1024;
    const int EB16 = (E + 4095) / 4096;            // 123
    const int FX16 = EB16 * 8;                     // 984 fill x-blocks
    const int CVR  = MP_RNA / 2, CVP = MP_PROT / 2;
    const int CV   = CVR + CVP;                    // 35072 cvt blocks
    const int XW   = (CV + 3) / 4;                 // 8768

    // --- ws layout ---
    char* ws = (char*)d_ws;
    size_t off = 0;
    u16*   Y16   = (u16*)  (ws + off); off += (size_t)MP_ALL * 1024 * 2;  // L0 [*,1024]; L1 aliases [*,512]
    u16*   Ahbig = (u16*)  (ws + off); off += (size_t)MP_ALL * 1024 * 2;
    u16*   B0h   = (u16*)  (ws + off); off += (size_t)1024 * 1024 * 2;
    u16*   B1h   = (u16*)  (ws + off); off += (size_t)512 * 512 * 2;
    size_t base_bytes = off;

    u16* AhR = Ahbig;                               // layer-1 A views [MP_ALL][512]
    u16* AhP = Ahbig + (size_t)MP_RNA * 512;

    // CSR scratch (ev + packed rows + meta)
    size_t csr_bytes = 0;
    csr_bytes += (size_t)S * E * 8 * 2;                       // evR + evP
    csr_bytes += (size_t)S * E * 2 * 2;                       // r16R + r16P
    csr_bytes += ((size_t)S * (NRNA * 2 + NP1_R + NB_R)) * 4;
    csr_bytes += ((size_t)S * (NPROT * 2 + NP1_P + NB_P)) * 4;
    const bool csr_in_ws = (ws_size >= base_bytes + csr_bytes);

    char* csr = csr_in_ws ? (ws + base_bytes) : (char*)d_out;
    size_t coff = 0;
    int2*  evR     = (int2*) (csr + coff); coff += (size_t)S * E * 8;
    int2*  evP     = (int2*) (csr + coff); coff += (size_t)S * E * 8;
    u16*   r16R    = (u16*)  (csr + coff); coff += (size_t)S * E * 2;
    u16*   r16P    = (u16*)  (csr + coff); coff += (size_t)S * E * 2;
    int*   countsR = (int*)  (csr + coff); coff += (size_t)S * NRNA * 4;
    int*   rowptrR = (int*)  (csr + coff); coff += (size_t)S * NP1_R * 4;
    int*   cursorR = (int*)  (csr + coff); coff += (size_t)S * NRNA * 4;
    int*   bsumR   = (int*)  (csr + coff); coff += (size_t)S * NB_R * 4;
    int*   countsP = (int*)  (csr + coff); coff += (size_t)S * NPROT * 4;
    int*   rowptrP = (int*)  (csr + coff); coff += (size_t)S * NP1_P * 4;
    int*   cursorP = (int*)  (csr + coff); coff += (size_t)S * NPROT * 4;
    int*   bsumP   = (int*)  (csr + coff); coff += (size_t)S * NB_P * 4;

    dim3 blk(256);
    float* out = (float*)d_out;

    // --- pack weights ---
    pack_b0_kernel<<<(1024 * 1024) / 256, blk, 0, stream>>>(w0, sw0, B0h);
    pack_b1_kernel<<<(512 * 512) / 256, blk, 0, stream>>>(w1, sw1, B1h);

    // --- CSR build prefix (pack+hist merged) ---
    zero2_i32_kernel<<<(S * NRNA + 255) / 256, blk, 0, stream>>>(countsR, S * NRNA,
                                                                 countsP, S * NPROT);
    pack_hist2_kernel<<<dim3(EB4, S, 2), blk, 0, stream>>>(
        rna_rows, prot_rows, r16R, r16P, countsR, countsP, NRNA, NPROT, E);
    scan_block2_kernel<<<dim3(NB_R, S, 2), blk, 0, stream>>>(
        countsR, rowptrR, bsumR, NRNA, NP1_R, NB_R,
        countsP, rowptrP, bsumP, NPROT, NP1_P, NB_P);
    scan_aux2_kernel<<<8, blk, 0, stream>>>(bsumR, NB_R, bsumP, NB_P);
    finalize2_kernel<<<dim3(NB_R, S, 2), blk, 0, stream>>>(
        rowptrR, bsumR, cursorR, NRNA, NP1_R, NB_R,
        rowptrP, bsumP, cursorP, NPROT, NP1_P, NB_P, E);

    // --- FUSED cvt ∥ fill (both LDS-free, 8 blocks/CU) ---
    fused_cvt_fill_kernel<<<dim3(XW, 4, 3), blk, 0, stream>>>(
        H_rna, H_prot, Ahbig, Ahbig + (size_t)MP_RNA * 1024, CVR, CV, XW,
        r16R, rna_cols, rna_vals, r16P, prot_cols, prot_vals,
        cursorR, cursorP, evR, evP, NRNA, NPROT, E, FX16);

    // --- layer 0 GEMM (standalone, r18 form) ---
    gemm_bf16_kernel<<<8 * (MP_ALL / 128), blk, 0, stream>>>(
        Ahbig, B0h, Y16, 1024, 1024, 7, 3);

    // --- layer 0 SpMM: Ah = bf16(relu(base + agg)) ---
    spmm2_kernel<128, 1><<<NRNA + NPROT, blk, 0, stream>>>(
        rowptrR, rowptrP, NP1_R, NP1_P, evR, evP,
        Y16 + (size_t)MP_RNA * 1024,      // RNA gathers prot tmp (cols 0..511)
        Y16,                              // PROT gathers rna tmp
        1024,
        Y16 + 512, Y16 + (size_t)MP_RNA * 1024 + 512, 1024,   // bf16 base halves
        AhR, AhP, nullptr, nullptr, 512,
        NRNA, E);

    // --- zero layer-1 A pad rows ---
    zero_u16_kernel<<<(48 * 512 + 255) / 256, blk, 0, stream>>>(
        AhR + (size_t)NRNA * 512, 48 * 512);
    zero_u16_kernel<<<(96 * 512 + 255) / 256, blk, 0, stream>>>(
        AhP + (size_t)NPROT * 512, 96 * 512);

    // --- layer 1: one GEMM (N=K=512), Y16_1 aliases Y16 [MP_ALL][512] ---
    gemm_bf16_kernel<<<4 * (MP_ALL / 128), blk, 0, stream>>>(
        Ahbig, B1h, Y16, 512, 512, 3, 2);

    // --- layer 1 SpMM ---
    if (csr_in_ws) {
        spmm2_kernel<64, 2><<<NRNA + NPROT, blk, 0, stream>>>(
            rowptrR, rowptrP, NP1_R, NP1_P, evR, evP,
            Y16 + (size_t)MP_RNA * 512, Y16, 512,
            Y16 + 256, Y16 + (size_t)MP_RNA * 512 + 256, 512,
            nullptr, nullptr,
            out, out + (size_t)NRNA * 256, 256,
            NRNA, E);
    } else {
        spmm2_kernel<64, 0><<<NRNA + NPROT, blk, 0, stream>>>(
            rowptrR, rowptrP, NP1_R, NP1_P, evR, evP,
            Y16 + (size_t)MP_RNA * 512, Y16, 512,
            Y16 + 256, Y16 + (size_t)MP_RNA * 512 + 256, 512,
            nullptr, nullptr,
            nullptr, nullptr, 0,
            NRNA, E);
        relu_out_kernel<<<(NRNA * 256) / 256, blk, 0, stream>>>(Y16, 512, 256, out, NRNA);
        relu_out_kernel<<<(NPROT * 256) / 256, blk, 0, stream>>>(
            Y16 + (size_t)MP_RNA * 512, 512, 256, out + (size_t)NRNA * 256, NPROT);
    }
}

// Round 24
// 958.541 us; speedup vs baseline: 1.0989x; 1.0055x over previous
//
#include <hip/hip_runtime.h>
#include <hip/hip_bf16.h>

// ---------------------------------------------------------------------------
// StackGCNEncoder on MI355X — round 24 (= round 23 + NT cvt streams):
//   cvt_body uses NON-TEMPORAL loads (H, read-once) and stores (Ahbig,
//   write-once, not re-read in-kernel) -> cvt streams bypass L2, stop
//   evicting fill's partially-written ev lines -> WRITE amplification
//   (371 MB vs 175 payload) drops. Everything else identical to round 23
//   (measured best 962-964 us).
// ---------------------------------------------------------------------------

typedef unsigned short u16;
typedef short s16x8 __attribute__((ext_vector_type(8)));
typedef float f32x4 __attribute__((ext_vector_type(4)));
typedef __attribute__((ext_vector_type(8))) unsigned short u16x8;
typedef unsigned long long u64;

__device__ __forceinline__ u16 f2bf(float x) {            // RNE f32->bf16
    unsigned u = __float_as_uint(x);
    return (u16)((u + 0x7fff + ((u >> 16) & 1)) >> 16);
}
__device__ __forceinline__ float bf2f(u16 h) {
    return __uint_as_float(((unsigned)h) << 16);
}

__device__ __forceinline__ void gload16(const u16* g, u16* l) {
    __builtin_amdgcn_global_load_lds(
        (const __attribute__((address_space(1))) unsigned int*)g,
        (__attribute__((address_space(3))) unsigned int*)l,
        16, 0, 0);
}

// ---------------------------------------------------------------------------
// bf16 GEMM (r18/r20 form): Y16 = A x B^T, all-bf16 out. 128x128, BK=32.
// ---------------------------------------------------------------------------
__global__ __launch_bounds__(256)
void gemm_bf16_kernel(const u16* __restrict__ Ah, const u16* __restrict__ Bh,
                      u16* __restrict__ Y, int ldy,
                      int K, int nxmask, int nxshift)
{
    __shared__ u16 lds[2][2][4096];   // 32 KB

    const int nwg = gridDim.x;
    const int q   = nwg >> 3, r8 = nwg & 7;
    const int xcd = blockIdx.x & 7, pos = blockIdx.x >> 3;
    const int lin = (xcd < r8 ? xcd * (q + 1) : r8 * (q + 1) + (xcd - r8) * q) + pos;
    const int bm0 = (lin >> nxshift) * 128;
    const int bn0 = (lin & nxmask) * 128;

    const int tid  = threadIdx.x;
    const int lane = tid & 63;
    const int wid  = tid >> 6;
    const int wr   = wid >> 1;
    const int wc   = wid & 1;

    const int srow = tid >> 2;
    const int scol = ((tid & 3) ^ ((tid >> 3) & 3)) * 8;   // u16 units
    const size_t aoff0 = (size_t)(bm0 + srow) * K + scol;
    const size_t aoff1 = (size_t)(bm0 + srow + 64) * K + scol;
    const size_t boff0 = (size_t)(bn0 + srow) * K + scol;
    const size_t boff1 = (size_t)(bn0 + srow + 64) * K + scol;
    const int c0 = tid * 8;
    const int c1 = 2048 + tid * 8;

    u16* L0 = &lds[0][0][0];              // buffer stride 8192 u16

    f32x4 zero = {0.f, 0.f, 0.f, 0.f};
    f32x4 acc[4][4];
    #pragma unroll
    for (int i = 0; i < 4; ++i)
        #pragma unroll
        for (int j = 0; j < 4; ++j) acc[i][j] = zero;

    const int fchunk = (((lane >> 4) ^ ((lane >> 1) & 3))) * 8;
    const int a_fr = (wr * 64 + (lane & 15)) * 32 + fchunk;
    const int b_fr = (wc * 64 + (lane & 15)) * 32 + fchunk;

    const int nk = K >> 5;

    {
        u16* L = L0;
        gload16(Ah + aoff0, L + c0);          gload16(Ah + aoff1, L + c1);
        gload16(Bh + boff0, L + 4096 + c0);   gload16(Bh + boff1, L + 4096 + c1);
    }
    int cur = 0;
    for (int t = 0; t < nk; ++t) {
        if (t + 1 < nk) {
            const int k0 = (t + 1) * 32;
            u16* L = L0 + (cur ^ 1) * 8192;
            gload16(Ah + aoff0 + k0, L + c0);         gload16(Ah + aoff1 + k0, L + c1);
            gload16(Bh + boff0 + k0, L + 4096 + c0);  gload16(Bh + boff1 + k0, L + 4096 + c1);
            asm volatile("s_waitcnt vmcnt(4)\n\ts_barrier" ::: "memory");
        } else {
            asm volatile("s_waitcnt vmcnt(0)\n\ts_barrier" ::: "memory");
        }
        const u16* L = L0 + cur * 8192;
        s16x8 bh[4];
        #pragma unroll
        for (int nf = 0; nf < 4; ++nf)
            bh[nf] = *(const s16x8*)(L + 4096 + b_fr + nf * 512);
        #pragma unroll
        for (int mf = 0; mf < 4; ++mf) {
            s16x8 ahv = *(const s16x8*)(L + a_fr + mf * 512);
            #pragma unroll
            for (int nf = 0; nf < 4; ++nf)
                acc[mf][nf] = __builtin_amdgcn_mfma_f32_16x16x32_bf16(ahv, bh[nf], acc[mf][nf], 0, 0, 0);
        }
        asm volatile("s_barrier" ::: "memory");
        cur ^= 1;
    }

    #pragma unroll
    for (int mf = 0; mf < 4; ++mf) {
        const int row0 = bm0 + wr * 64 + mf * 16 + (lane >> 4) * 4;
        #pragma unroll
        for (int nf = 0; nf < 4; ++nf) {
            const int col = bn0 + wc * 64 + nf * 16 + (lane & 15);
            #pragma unroll
            for (int r = 0; r < 4; ++r)
                Y[(size_t)(row0 + r) * ldy + col] = f2bf(acc[mf][nf][r]);
        }
    }
}

// ---------------------------------------------------------------------------
// cvt body: f32 [M][1024] -> bf16 (8 elems/thread), zero-padded rows.
// NON-TEMPORAL streams: H read-once, Ahbig write-once (not re-read in-kernel).
// ---------------------------------------------------------------------------
__device__ __forceinline__
void cvt_body(int bid, const float* __restrict__ A, u16* __restrict__ Hh, int M)
{
    const size_t g  = (size_t)bid * 256 + threadIdx.x;
    const size_t i8 = g * 8;
    const int row   = (int)(i8 >> 10);
    f32x4 a = {0.f, 0.f, 0.f, 0.f}, b = {0.f, 0.f, 0.f, 0.f};
    if (row < M) {
        a = __builtin_nontemporal_load((const f32x4*)(A + i8));
        b = __builtin_nontemporal_load((const f32x4*)(A + i8 + 4));
    }
    u16x8 h;
    #pragma unroll
    for (int j = 0; j < 4; ++j) { h[j] = f2bf(a[j]); h[4 + j] = f2bf(b[j]); }
    __builtin_nontemporal_store(h, (u16x8*)(Hh + i8));
}

// ---------------------------------------------------------------------------
// fill body: 16 edges/thread, row-sliced XCD-affine, u16 rows.
// ---------------------------------------------------------------------------
__device__ __forceinline__
void fill_body16(int fx, int s, int side,
                 const u16* __restrict__ r16R, const int* __restrict__ colsR,
                 const float* __restrict__ valsR,
                 const u16* __restrict__ r16P, const int* __restrict__ colsP,
                 const float* __restrict__ valsP,
                 int* __restrict__ curR, int* __restrict__ curP,
                 int2* __restrict__ evR, int2* __restrict__ evP,
                 int NR, int NP, int E)
{
    const int slice = fx & 7;
    const int chunk = fx >> 3;
    const int N          = side ? NP : NR;
    const u16* r16       = side ? r16P : r16R;
    const int* cols      = side ? colsP : colsR;
    const float* vals    = side ? valsP : valsR;
    int* cursor          = side ? curP : curR;
    int2* ev             = side ? evP : evR;

    const int Nsl = (N + 7) >> 3;
    const int r0 = slice * Nsl;
    const int r1 = min(N, r0 + Nsl);

    const int e0 = chunk * 4096 + threadIdx.x * 16;
    if (e0 >= E) return;
    const size_t base = (size_t)s * E;

    if (e0 + 16 <= E) {
        u64 rq[4];
        #pragma unroll
        for (int g = 0; g < 4; ++g)
            rq[g] = *(const u64*)(r16 + base + e0 + g * 4);
        #pragma unroll
        for (int g = 0; g < 4; ++g) {
            #pragma unroll
            for (int j = 0; j < 4; ++j) {
                int r = (int)(u16)(rq[g] >> (16 * j));
                if (r >= r0 && r < r1) {
                    int idx = e0 + g * 4 + j;
                    int pos = atomicAdd(cursor + s * N + r, 1);
                    ev[base + pos] = make_int2(cols[base + idx],
                                               __float_as_int(vals[base + idx]));
                }
            }
        }
    } else {
        for (int j = 0; j < 16 && e0 + j < E; ++j) {
            int r = (int)r16[base + e0 + j];
            if (r >= r0 && r < r1) {
                int pos = atomicAdd(cursor + s * N + r, 1);
                ev[base + pos] = make_int2(cols[base + e0 + j],
                                           __float_as_int(vals[base + e0 + j]));
            }
        }
    }
}

// ---------------------------------------------------------------------------
// FUSED cvt ∥ fill: grid (XW, 4, 3). z==0 -> cvt (id = y*XW+x);
// z in {1,2} -> fill side z-1, s=y, fx=x (x < FX16). No LDS -> 8 blocks/CU.
// ---------------------------------------------------------------------------
__global__ __launch_bounds__(256)
void fused_cvt_fill_kernel(const float* __restrict__ H_rna, const float* __restrict__ H_prot,
                           u16* __restrict__ AhR_full, u16* __restrict__ AhP_full,
                           int CVR, int CV, int XW,
                           const u16* __restrict__ r16R, const int* __restrict__ colsR,
                           const float* __restrict__ valsR,
                           const u16* __restrict__ r16P, const int* __restrict__ colsP,
                           const float* __restrict__ valsP,
                           int* __restrict__ curR, int* __restrict__ curP,
                           int2* __restrict__ evR, int2* __restrict__ evP,
                           int NR, int NP, int E, int FX16)
{
    const int z = blockIdx.z;
    if (z == 0) {
        int id = blockIdx.y * XW + blockIdx.x;
        if (id >= CV) return;
        if (id < CVR) cvt_body(id, H_rna, AhR_full, NR);
        else          cvt_body(id - CVR, H_prot, AhP_full, NP);
    } else {
        if ((int)blockIdx.x >= FX16) return;
        fill_body16(blockIdx.x, blockIdx.y, z - 1,
                    r16R, colsR, valsR, r16P, colsP, valsP,
                    curR, curP, evR, evP, NR, NP, E);
    }
}

__global__ __launch_bounds__(256)
void zero_u16_kernel(u16* __restrict__ a, int n)
{
    int i = blockIdx.x * 256 + threadIdx.x;
    if (i < n) a[i] = 0;
}

// ---------------------------------------------------------------------------
// CSR build
// ---------------------------------------------------------------------------
__global__ __launch_bounds__(256)
void zero2_i32_kernel(int* __restrict__ a, int na, int* __restrict__ b, int nb)
{
    int i = blockIdx.x * 256 + threadIdx.x;
    if (i < na) a[i] = 0;
    if (i < nb) b[i] = 0;
}

// merged: pack rows int32 -> u16 AND histogram, one read pass. 4 edges/thread.
__global__ __launch_bounds__(256)
void pack_hist2_kernel(const int* __restrict__ rowsR, const int* __restrict__ rowsP,
                       u16* __restrict__ r16R, u16* __restrict__ r16P,
                       int* __restrict__ cntR, int* __restrict__ cntP,
                       int NR, int NP, int E)
{
    int s = blockIdx.y;
    int e = (blockIdx.x * 256 + threadIdx.x) * 4;
    if (e >= E) return;
    const int* rows = blockIdx.z ? rowsP : rowsR;
    u16* r16 = blockIdx.z ? r16P : r16R;
    int* cnt = blockIdx.z ? cntP : cntR;
    const int N = blockIdx.z ? NP : NR;
    size_t base = (size_t)s * E;
    if (e + 4 <= E) {
        int4 r4 = *(const int4*)(rows + base + e);
        u16 p[4] = {(u16)r4.x, (u16)r4.y, (u16)r4.z, (u16)r4.w};
        *(u64*)(r16 + base + e) = *(const u64*)p;
        atomicAdd(cnt + s * N + r4.x, 1);
        atomicAdd(cnt + s * N + r4.y, 1);
        atomicAdd(cnt + s * N + r4.z, 1);
        atomicAdd(cnt + s * N + r4.w, 1);
    } else {
        for (int j = 0; j < 4 && e + j < E; ++j) {
            int r = rows[base + e + j];
            r16[base + e + j] = (u16)r;
            atomicAdd(cnt + s * N + r, 1);
        }
    }
}

__global__ __launch_bounds__(256)
void scan_block2_kernel(const int* __restrict__ cR, int* __restrict__ rpR,
                        int* __restrict__ bsR, int NR, int np1R, int NBR,
                        const int* __restrict__ cP, int* __restrict__ rpP,
                        int* __restrict__ bsP, int NP, int np1P, int NBP)
{
    const int side = blockIdx.z;
    const int NB = side ? NBP : NBR;
    if ((int)blockIdx.x >= NB) return;
    const int N = side ? NP : NR;
    const int np1 = side ? np1P : np1R;
    const int* counts = side ? cP : cR;
    int* rowptr = side ? rpP : rpR;
    int* blocksum = side ? bsP : bsR;

    __shared__ int sd[256];
    int s = blockIdx.y;
    int i = blockIdx.x * 256 + threadIdx.x;
    int tid = threadIdx.x;
    int v = (i < N) ? counts[s * N + i] : 0;
    sd[tid] = v;
    __syncthreads();
    #pragma unroll
    for (int off = 1; off < 256; off <<= 1) {
        int t = (tid >= off) ? sd[tid - off] : 0;
        __syncthreads();
        sd[tid] += t;
        __syncthreads();
    }
    if (i < N) rowptr[s * np1 + i] = sd[tid] - v;
    if (tid == 255) blocksum[s * NB + blockIdx.x] = sd[255];
}

__global__ __launch_bounds__(256)
void scan_aux2_kernel(int* __restrict__ bsR, int NBR, int* __restrict__ bsP, int NBP)
{
    const int side = blockIdx.x >> 2;
    const int s = blockIdx.x & 3;
    int* blocksum = side ? bsP : bsR;
    const int NB = side ? NBP : NBR;

    __shared__ int sd[256];
    int tid = threadIdx.x;
    int v = (tid < NB) ? blocksum[s * NB + tid] : 0;
    sd[tid] = v;
    __syncthreads();
    #pragma unroll
    for (int off = 1; off < 256; off <<= 1) {
        int t = (tid >= off) ? sd[tid - off] : 0;
        __syncthreads();
        sd[tid] += t;
        __syncthreads();
    }
    if (tid < NB) blocksum[s * NB + tid] = sd[tid] - v;
}

__global__ __launch_bounds__(256)
void finalize2_kernel(int* __restrict__ rpR, const int* __restrict__ bsR,
                      int* __restrict__ curR, int NR, int np1R, int NBR,
                      int* __restrict__ rpP, const int* __restrict__ bsP,
                      int* __restrict__ curP, int NP, int np1P, int NBP, int E)
{
    const int side = blockIdx.z;
    const int NB = side ? NBP : NBR;
    if ((int)blockIdx.x >= NB) return;
    const int N = side ? NP : NR;
    const int np1 = side ? np1P : np1R;
    int* rowptr = side ? rpP : rpR;
    const int* blocksum = side ? bsP : bsR;
    int* cursor = side ? curP : curR;

    int s = blockIdx.y;
    int i = blockIdx.x * 256 + threadIdx.x;
    if (i < N) {
        int v = rowptr[s * np1 + i] + blocksum[s * NB + blockIdx.x];
        rowptr[s * np1 + i] = v;
        cursor[s * N + i] = v;
    }
    if (i == N) rowptr[s * np1 + N] = E;
}

// ---------------------------------------------------------------------------
// CSR SpMM, quarter/eighth-wave edge parallelism (r17/r20 form, unroll-2).
// ---------------------------------------------------------------------------
template<int KCH, int MODE>
__global__ __launch_bounds__(256)
void spmm2_kernel(const int* __restrict__ rpR, const int* __restrict__ rpP,
                  int np1R, int np1P,
                  const int2* __restrict__ evRg, const int2* __restrict__ evPg,
                  const u16* __restrict__ InR, const u16* __restrict__ InP, int ldi,
                  u16* __restrict__ BaseR, u16* __restrict__ BaseP, int ldb,
                  u16* __restrict__ OHR, u16* __restrict__ OHP,
                  float* __restrict__ OFR, float* __restrict__ OFP, int ldo,
                  int NR, int E)
{
    int r = blockIdx.x;
    const int s    = threadIdx.x >> 6;
    const int lane = threadIdx.x & 63;
    const int* rp; const int2* ev; const u16* In; u16* Base; int np1;
    u16* OH; float* OF;
    if (r < NR) { rp = rpR; ev = evRg; In = InR; Base = BaseR; np1 = np1R;
                  OH = OHR; OF = OFR; }
    else { r -= NR; rp = rpP; ev = evPg; In = InP; Base = BaseP; np1 = np1P;
           OH = OHP; OF = OFP; }
    int e0 = __builtin_amdgcn_readfirstlane(rp[s * np1 + r]);
    int e1 = __builtin_amdgcn_readfirstlane(rp[s * np1 + r + 1]);
    if (MODE == 0 && e0 == e1) return;
    ev += (size_t)s * E;

    if (KCH == 128) {
        const int qg = lane >> 4;
        const int ql = lane & 15;
        const int col = s * 128 + ql * 8;
        float a[8] = {0.f, 0.f, 0.f, 0.f, 0.f, 0.f, 0.f, 0.f};
        int e = e0;
        for (; e + 7 < e1; e += 8) {
            int2 p0 = ev[e + qg];
            int2 p1 = ev[e + 4 + qg];
            float v0 = __int_as_float(p0.y);
            float v1 = __int_as_float(p1.y);
            u16x8 x0 = *(const u16x8*)(In + (size_t)p0.x * ldi + col);
            u16x8 x1 = *(const u16x8*)(In + (size_t)p1.x * ldi + col);
            #pragma unroll
            for (int j = 0; j < 8; ++j)
                a[j] += v0 * bf2f(x0[j]) + v1 * bf2f(x1[j]);
        }
        for (; e < e1; e += 4) {
            if (e + qg < e1) {
                int2 pv = ev[e + qg];
                float v = __int_as_float(pv.y);
                u16x8 x = *(const u16x8*)(In + (size_t)pv.x * ldi + col);
                #pragma unroll
                for (int j = 0; j < 8; ++j)
                    a[j] += v * bf2f(x[j]);
            }
        }
        #pragma unroll
        for (int j = 0; j < 8; ++j) {
            a[j] += __shfl_xor(a[j], 16);
            a[j] += __shfl_xor(a[j], 32);
        }
        if (lane < 16) {
            u16x8* bp = (u16x8*)(Base + (size_t)r * ldb + col);
            u16x8 b = *bp;
            if (MODE == 0) {
                u16x8 nb;
                #pragma unroll
                for (int j = 0; j < 8; ++j) nb[j] = f2bf(bf2f(b[j]) + a[j]);
                *bp = nb;
            } else if (MODE == 1) {
                u16x8 h;
                #pragma unroll
                for (int j = 0; j < 8; ++j) h[j] = f2bf(fmaxf(bf2f(b[j]) + a[j], 0.f));
                *(u16x8*)(OH + (size_t)r * ldo + col) = h;
            } else {
                f32x4 o0, o1;
                #pragma unroll
                for (int j = 0; j < 4; ++j) {
                    o0[j] = fmaxf(bf2f(b[j]) + a[j], 0.f);
                    o1[j] = fmaxf(bf2f(b[4 + j]) + a[4 + j], 0.f);
                }
                *(f32x4*)(OF + (size_t)r * ldo + col) = o0;
                *(f32x4*)(OF + (size_t)r * ldo + col + 4) = o1;
            }
        }
    } else {   // KCH == 64
        const int og = lane >> 3;
        const int ol = lane & 7;
        const int col = s * 64 + ol * 8;
        float a[8] = {0.f, 0.f, 0.f, 0.f, 0.f, 0.f, 0.f, 0.f};
        int e = e0;
        for (; e + 15 < e1; e += 16) {
            int2 p0 = ev[e + og];
            int2 p1 = ev[e + 8 + og];
            float v0 = __int_as_float(p0.y);
            float v1 = __int_as_float(p1.y);
            u16x8 x0 = *(const u16x8*)(In + (size_t)p0.x * ldi + col);
            u16x8 x1 = *(const u16x8*)(In + (size_t)p1.x * ldi + col);
            #pragma unroll
            for (int j = 0; j < 8; ++j)
                a[j] += v0 * bf2f(x0[j]) + v1 * bf2f(x1[j]);
        }
        for (; e < e1; e += 8) {
            if (e + og < e1) {
                int2 pv = ev[e + og];
                float v = __int_as_float(pv.y);
                u16x8 x = *(const u16x8*)(In + (size_t)pv.x * ldi + col);
                #pragma unroll
                for (int j = 0; j < 8; ++j)
                    a[j] += v * bf2f(x[j]);
            }
        }
        #pragma unroll
        for (int j = 0; j < 8; ++j) {
            a[j] += __shfl_xor(a[j], 8);
            a[j] += __shfl_xor(a[j], 16);
            a[j] += __shfl_xor(a[j], 32);
        }
        if (lane < 8) {
            u16x8* bp = (u16x8*)(Base + (size_t)r * ldb + col);
            u16x8 b = *bp;
            if (MODE == 0) {
                u16x8 nb;
                #pragma unroll
                for (int j = 0; j < 8; ++j) nb[j] = f2bf(bf2f(b[j]) + a[j]);
                *bp = nb;
            } else {
                f32x4 o0, o1;
                #pragma unroll
                for (int j = 0; j < 4; ++j) {
                    o0[j] = fmaxf(bf2f(b[j]) + a[j], 0.f);
                    o1[j] = fmaxf(bf2f(b[4 + j]) + a[4 + j], 0.f);
                }
                *(f32x4*)(OF + (size_t)r * ldo + col) = o0;
                *(f32x4*)(OF + (size_t)r * ldo + col + 4) = o1;
            }
        }
    }
}

// fallback-only final relu over bf16 base
__global__ __launch_bounds__(256)
void relu_out_kernel(const u16* __restrict__ Z, int ld, int coff,
                     float* __restrict__ out, int M)
{
    int g = blockIdx.x * 256 + threadIdx.x;
    if (g >= M * 256) return;
    int row = g >> 8;
    int col = g & 255;
    out[g] = fmaxf(bf2f(Z[(size_t)row * ld + coff + col]), 0.f);
}

// ---------------------------------------------------------------------------
// weight packing (transposed [N][K], bf16)
// ---------------------------------------------------------------------------
__global__ __launch_bounds__(256)
void pack_b0_kernel(const float* __restrict__ w0, const float* __restrict__ sw0,
                    u16* __restrict__ Bh)
{
    int g = blockIdx.x * 256 + threadIdx.x;
    int j = g >> 10, d = g & 1023;
    float v;
    if (j < 512) v = w0[((size_t)(j >> 7) * 1024 + d) * 128 + (j & 127)];
    else         v = sw0[(size_t)d * 512 + (j - 512)];
    Bh[g] = f2bf(v);
}

__global__ __launch_bounds__(256)
void pack_b1_kernel(const float* __restrict__ w1, const float* __restrict__ sw1,
                    u16* __restrict__ Bh)
{
    int g = blockIdx.x * 256 + threadIdx.x;
    int j = g >> 9, d = g & 511;
    float v;
    if (j < 256) v = w1[((size_t)(j >> 6) * 512 + d) * 64 + (j & 63)];
    else         v = sw1[(size_t)d * 256 + (j - 256)];
    Bh[g] = f2bf(v);
}

extern "C" void kernel_launch(void* const* d_in, const int* in_sizes, int n_in,
                              void* d_out, int out_size, void* d_ws, size_t ws_size,
                              hipStream_t stream)
{
    const int*   rna_rows  = (const int*)  d_in[0];
    const int*   rna_cols  = (const int*)  d_in[1];
    const float* rna_vals  = (const float*)d_in[2];
    const int*   prot_rows = (const int*)  d_in[3];
    const int*   prot_cols = (const int*)  d_in[4];
    const float* prot_vals = (const float*)d_in[5];
    const float* H_rna     = (const float*)d_in[6];
    const float* H_prot    = (const float*)d_in[7];
    const float* w0        = (const float*)d_in[8];
    const float* sw0       = (const float*)d_in[9];
    const float* w1        = (const float*)d_in[10];
    const float* sw1       = (const float*)d_in[11];

    const int NRNA = 50000, NPROT = 20000, S = 4, E = 500000;
    const int MP_RNA = 50048, MP_PROT = 20096;
    const int MP_ALL = MP_RNA + MP_PROT;           // 70144 = 548 * 128
    const int NP1_R = NRNA + 1, NP1_P = NPROT + 1;
    const int NB_R = (NRNA + 255) / 256;
    const int NB_P = (NPROT + 255) / 256;
    const int EB4  = (E + 1023) / 1024;
    const int EB16 = (E + 4095) / 4096;            // 123
    const int FX16 = EB16 * 8;                     // 984 fill x-blocks
    const int CVR  = MP_RNA / 2, CVP = MP_PROT / 2;
    const int CV   = CVR + CVP;                    // 35072 cvt blocks
    const int XW   = (CV + 3) / 4;                 // 8768

    // --- ws layout ---
    char* ws = (char*)d_ws;
    size_t off = 0;
    u16*   Y16   = (u16*)  (ws + off); off += (size_t)MP_ALL * 1024 * 2;  // L0 [*,1024]; L1 aliases [*,512]
    u16*   Ahbig = (u16*)  (ws + off); off += (size_t)MP_ALL * 1024 * 2;
    u16*   B0h   = (u16*)  (ws + off); off += (size_t)1024 * 1024 * 2;
    u16*   B1h   = (u16*)  (ws + off); off += (size_t)512 * 512 * 2;
    size_t base_bytes = off;

    u16* AhR = Ahbig;                               // layer-1 A views [MP_ALL][512]
    u16* AhP = Ahbig + (size_t)MP_RNA * 512;

    // CSR scratch (ev + packed rows + meta)
    size_t csr_bytes = 0;
    csr_bytes += (size_t)S * E * 8 * 2;                       // evR + evP
    csr_bytes += (size_t)S * E * 2 * 2;                       // r16R + r16P
    csr_bytes += ((size_t)S * (NRNA * 2 + NP1_R + NB_R)) * 4;
    csr_bytes += ((size_t)S * (NPROT * 2 + NP1_P + NB_P)) * 4;
    const bool csr_in_ws = (ws_size >= base_bytes + csr_bytes);

    char* csr = csr_in_ws ? (ws + base_bytes) : (char*)d_out;
    size_t coff = 0;
    int2*  evR     = (int2*) (csr + coff); coff += (size_t)S * E * 8;
    int2*  evP     = (int2*) (csr + coff); coff += (size_t)S * E * 8;
    u16*   r16R    = (u16*)  (csr + coff); coff += (size_t)S * E * 2;
    u16*   r16P    = (u16*)  (csr + coff); coff += (size_t)S * E * 2;
    int*   countsR = (int*)  (csr + coff); coff += (size_t)S * NRNA * 4;
    int*   rowptrR = (int*)  (csr + coff); coff += (size_t)S * NP1_R * 4;
    int*   cursorR = (int*)  (csr + coff); coff += (size_t)S * NRNA * 4;
    int*   bsumR   = (int*)  (csr + coff); coff += (size_t)S * NB_R * 4;
    int*   countsP = (int*)  (csr + coff); coff += (size_t)S * NPROT * 4;
    int*   rowptrP = (int*)  (csr + coff); coff += (size_t)S * NP1_P * 4;
    int*   cursorP = (int*)  (csr + coff); coff += (size_t)S * NPROT * 4;
    int*   bsumP   = (int*)  (csr + coff); coff += (size_t)S * NB_P * 4;

    dim3 blk(256);
    float* out = (float*)d_out;

    // --- pack weights ---
    pack_b0_kernel<<<(1024 * 1024) / 256, blk, 0, stream>>>(w0, sw0, B0h);
    pack_b1_kernel<<<(512 * 512) / 256, blk, 0, stream>>>(w1, sw1, B1h);

    // --- CSR build prefix (pack+hist merged) ---
    zero2_i32_kernel<<<(S * NRNA + 255) / 256, blk, 0, stream>>>(countsR, S * NRNA,
                                                                 countsP, S * NPROT);
    pack_hist2_kernel<<<dim3(EB4, S, 2), blk, 0, stream>>>(
        rna_rows, prot_rows, r16R, r16P, countsR, countsP, NRNA, NPROT, E);
    scan_block2_kernel<<<dim3(NB_R, S, 2), blk, 0, stream>>>(
        countsR, rowptrR, bsumR, NRNA, NP1_R, NB_R,
        countsP, rowptrP, bsumP, NPROT, NP1_P, NB_P);
    scan_aux2_kernel<<<8, blk, 0, stream>>>(bsumR, NB_R, bsumP, NB_P);
    finalize2_kernel<<<dim3(NB_R, S, 2), blk, 0, stream>>>(
        rowptrR, bsumR, cursorR, NRNA, NP1_R, NB_R,
        rowptrP, bsumP, cursorP, NPROT, NP1_P, NB_P, E);

    // --- FUSED cvt ∥ fill (both LDS-free, 8 blocks/CU; cvt streams NT) ---
    fused_cvt_fill_kernel<<<dim3(XW, 4, 3), blk, 0, stream>>>(
        H_rna, H_prot, Ahbig, Ahbig + (size_t)MP_RNA * 1024, CVR, CV, XW,
        r16R, rna_cols, rna_vals, r16P, prot_cols, prot_vals,
        cursorR, cursorP, evR, evP, NRNA, NPROT, E, FX16);

    // --- layer 0 GEMM ---
    gemm_bf16_kernel<<<8 * (MP_ALL / 128), blk, 0, stream>>>(
        Ahbig, B0h, Y16, 1024, 1024, 7, 3);

    // --- layer 0 SpMM: Ah = bf16(relu(base + agg)) ---
    spmm2_kernel<128, 1><<<NRNA + NPROT, blk, 0, stream>>>(
        rowptrR, rowptrP, NP1_R, NP1_P, evR, evP,
        Y16 + (size_t)MP_RNA * 1024,      // RNA gathers prot tmp (cols 0..511)
        Y16,                              // PROT gathers rna tmp
        1024,
        Y16 + 512, Y16 + (size_t)MP_RNA * 1024 + 512, 1024,   // bf16 base halves
        AhR, AhP, nullptr, nullptr, 512,
        NRNA, E);

    // --- zero layer-1 A pad rows ---
    zero_u16_kernel<<<(48 * 512 + 255) / 256, blk, 0, stream>>>(
        AhR + (size_t)NRNA * 512, 48 * 512);
    zero_u16_kernel<<<(96 * 512 + 255) / 256, blk, 0, stream>>>(
        AhP + (size_t)NPROT * 512, 96 * 512);

    // --- layer 1: one GEMM (N=K=512), Y16_1 aliases Y16 [MP_ALL][512] ---
    gemm_bf16_kernel<<<4 * (MP_ALL / 128), blk, 0, stream>>>(
        Ahbig, B1h, Y16, 512, 512, 3, 2);

    // --- layer 1 SpMM ---
    if (csr_in_ws) {
        spmm2_kernel<64, 2><<<NRNA + NPROT, blk, 0, stream>>>(
            rowptrR, rowptrP, NP1_R, NP1_P, evR, evP,
            Y16 + (size_t)MP_RNA * 512, Y16, 512,
            Y16 + 256, Y16 + (size_t)MP_RNA * 512 + 256, 512,
            nullptr, nullptr,
            out, out + (size_t)NRNA * 256, 256,
            NRNA, E);
    } else {
        spmm2_kernel<64, 0><<<NRNA + NPROT, blk, 0, stream>>>(
            rowptrR, rowptrP, NP1_R, NP1_P, evR, evP,
            Y16 + (size_t)MP_RNA * 512, Y16, 512,
            Y16 + 256, Y16 + (size_t)MP_RNA * 512 + 256, 512,
            nullptr, nullptr,
            nullptr, nullptr, 0,
            NRNA, E);
        relu_out_kernel<<<(NRNA * 256) / 256, blk, 0, stream>>>(Y16, 512, 256, out, NRNA);
        relu_out_kernel<<<(NPROT * 256) / 256, blk, 0, stream>>>(
            Y16 + (size_t)MP_RNA * 512, 512, 256, out + (size_t)NRNA * 256, NPROT);
    }
}